// Round 9
// baseline (4191.329 us; speedup 1.0000x reference)
//
#include <hip/hip_runtime.h>
#include <hip/hip_bf16.h>
#include <math.h>

#define NTOK 32768
#define CDIM 512
#define HDIM 1536
#define ENUM 8
#define SMAX 16384   // per-expert row-tile span (actual counts ~8192)
#define BK 32        // K-step; 64B LDS rows -> conflict-free b128 banking

typedef unsigned short u16;
typedef _Float16 f16x8 __attribute__((ext_vector_type(8)));
typedef float    f32x4 __attribute__((ext_vector_type(4)));
typedef int      i32x4 __attribute__((ext_vector_type(4)));
typedef u16      u16x4 __attribute__((ext_vector_type(4)));

__device__ __forceinline__ void gload16(void* lds, const void* g) {
    __builtin_amdgcn_global_load_lds(
        (const __attribute__((address_space(1))) void*)g,
        (__attribute__((address_space(3))) void*)lds, 16, 0, 0);
}

__device__ __forceinline__ u16 f2h(float f) {
    _Float16 h = (_Float16)f;
    return __builtin_bit_cast(u16, h);
}
__device__ __forceinline__ float h2f(u16 u) {
    return (float)__builtin_bit_cast(_Float16, u);
}

// ---------------- meta ----------------
__global__ void k_zero(int* __restrict__ meta) {
    if (threadIdx.x < 256) meta[threadIdx.x] = 0;
}

__global__ void k_offsets(const int* __restrict__ counts, int* __restrict__ offs) {
    if (threadIdx.x == 0) {
        int o = 0;
        for (int e = 0; e < ENUM; ++e) { offs[e] = o; o += counts[e * 16]; }
        offs[ENUM] = o;
    }
}

__global__ void k_diag(float* __restrict__ out, int n) {
    int i = blockIdx.x * 256 + threadIdx.x;
    if (i < n) out[i] = 12345.0f;
}

// ---------------- router: logits, top-2, gates, x->f16 (no atomics) --------
__global__ __launch_bounds__(256) void k_router(
    const float* __restrict__ x, const float* __restrict__ rw,
    u16* __restrict__ xh, int* __restrict__ sel, float* __restrict__ gate) {
    __shared__ float srw[ENUM * CDIM];
    int tid = threadIdx.x;
    for (int i = tid * 4; i < ENUM * CDIM; i += 256 * 4)
        *(float4*)&srw[i] = *(const float4*)&rw[i];
    __syncthreads();

    int wave = tid >> 6, lane = tid & 63;
    int n = blockIdx.x * 4 + wave;

    const float* xr = x + (size_t)n * CDIM + lane * 8;
    float4 a = *(const float4*)xr;
    float4 b = *(const float4*)(xr + 4);

    u16x4 p0 = { f2h(a.x), f2h(a.y), f2h(a.z), f2h(a.w) };
    u16x4 p1 = { f2h(b.x), f2h(b.y), f2h(b.z), f2h(b.w) };
    u16* xd = xh + (size_t)n * CDIM + lane * 8;
    *(u16x4*)xd = p0;
    *(u16x4*)(xd + 4) = p1;

    float part[ENUM];
#pragma unroll
    for (int e = 0; e < ENUM; ++e) {
        const float4* rp = (const float4*)&srw[e * CDIM + lane * 8];
        float4 r0 = rp[0], r1 = rp[1];
        part[e] = a.x * r0.x + a.y * r0.y + a.z * r0.z + a.w * r0.w
                + b.x * r1.x + b.y * r1.y + b.z * r1.z + b.w * r1.w;
    }
#pragma unroll
    for (int m = 32; m >= 1; m >>= 1) {
#pragma unroll
        for (int e = 0; e < ENUM; ++e) part[e] += __shfl_xor(part[e], m, 64);
    }

    if (lane == 0) {
        int e0 = 0; float m0 = part[0];
#pragma unroll
        for (int e = 1; e < ENUM; ++e) { if (part[e] > m0) { m0 = part[e]; e0 = e; } }
        int e1 = -1; float m1 = -1e30f;
#pragma unroll
        for (int e = 0; e < ENUM; ++e) { if (e != e0 && part[e] > m1) { m1 = part[e]; e1 = e; } }
        float g0 = 1.f / (1.f + __expf(m1 - m0));
        sel[2 * n] = e0;  sel[2 * n + 1] = e1;
        gate[2 * n] = g0; gate[2 * n + 1] = 1.f - g0;
    }
}

// ---------------- histogram of sel -> padded counts ----------------
__global__ __launch_bounds__(256) void k_hist(const int* __restrict__ sel,
                                              int* __restrict__ counts) {
    __shared__ int lc[ENUM];
    int tid = threadIdx.x;
    if (tid < ENUM) lc[tid] = 0;
    __syncthreads();
    int i = blockIdx.x * 1024 + tid;
#pragma unroll
    for (int k = 0; k < 4; ++k) atomicAdd(&lc[sel[i + k * 256]], 1);
    __syncthreads();
    if (tid < ENUM) atomicAdd(&counts[tid * 16], lc[tid]);
}

// ---------------- weights fp32 -> f16 ----------------
__global__ void k_convw(const float* __restrict__ w1, const float* __restrict__ wg,
                        const float* __restrict__ w2, u16* __restrict__ w1h,
                        u16* __restrict__ wgh, u16* __restrict__ w2h) {
    const int total = ENUM * HDIM * CDIM / 4;
    for (int i = blockIdx.x * blockDim.x + threadIdx.x; i < total;
         i += gridDim.x * blockDim.x) {
        float4 a = ((const float4*)w1)[i];
        u16x4 o1 = { f2h(a.x), f2h(a.y), f2h(a.z), f2h(a.w) };
        ((u16x4*)w1h)[i] = o1;
        float4 c = ((const float4*)wg)[i];
        u16x4 o2 = { f2h(c.x), f2h(c.y), f2h(c.z), f2h(c.w) };
        ((u16x4*)wgh)[i] = o2;
        float4 d = ((const float4*)w2)[i];
        u16x4 o3 = { f2h(d.x), f2h(d.y), f2h(d.z), f2h(d.w) };
        ((u16x4*)w2h)[i] = o3;
    }
}

// ---------------- build per-expert gather lists (block-local ranking) -------
__global__ __launch_bounds__(256) void k_perm(
    const int* __restrict__ sel, const float* __restrict__ gate,
    const int* __restrict__ offs, int* __restrict__ cursor,
    int* __restrict__ perm, float* __restrict__ pgate) {
    __shared__ int lc[ENUM];
    __shared__ int lbase[ENUM];
    int tid = threadIdx.x;
    if (tid < ENUM) lc[tid] = 0;
    __syncthreads();
    int i0 = blockIdx.x * 512;
    int p0 = i0 + tid, p1 = i0 + 256 + tid;
    int e0 = sel[p0], e1 = sel[p1];
    int r0 = atomicAdd(&lc[e0], 1);
    int r1 = atomicAdd(&lc[e1], 1);
    __syncthreads();
    if (tid < ENUM) lbase[tid] = atomicAdd(&cursor[tid * 16], lc[tid]);
    __syncthreads();
    int s0 = offs[e0] + lbase[e0] + r0;
    int s1 = offs[e1] + lbase[e1] + r1;
    perm[s0] = (p0 >> 1) | ((p0 & 1) << 31);
    pgate[s0] = gate[p0];
    perm[s1] = (p1 >> 1) | ((p1 & 1) << 31);
    pgate[s1] = gate[p1];
}

// ---------------- FFN1: h = silu(x w1^T) * (x wg^T) ------------------------
// 512-thread block, tile 256 slots x 128 h, 8 waves (2h x 4slot quadrants).
// 2-deep counted-vmcnt pipeline, 4 loads/wave/stage -> vmcnt(4).
__global__ __launch_bounds__(512, 4) void k_ffn1(
    int e0, const u16* __restrict__ xh, const u16* __restrict__ w1h,
    const u16* __restrict__ wgh, const int* __restrict__ perm,
    const int* __restrict__ offs, u16* __restrict__ hbuf) {
    int e  = e0 + (blockIdx.x >> 6);
    int rt = blockIdx.x & 63;
    int gbase = offs[e0];
    int base = offs[e];
    int cnt  = offs[e + 1] - base;
    if (cnt > SMAX) cnt = SMAX;
    int r0 = rt * 256;
    if (r0 >= cnt) return;
    int h0 = blockIdx.y * 128;

    __shared__ u16 tX[2][256 * BK];    // 16 KB per buffer
    __shared__ u16 tW1[2][128 * BK];   //  8 KB per buffer
    __shared__ u16 tWg[2][128 * BK];   //  8 KB per buffer
    __shared__ int stok[256];

    int tid = threadIdx.x, lane = tid & 63, wv = tid >> 6;
    if (tid < 256) {
        int r = r0 + tid;
        stok[tid] = (r < cnt) ? (perm[base + r] & 0x7fffffff) : 0;
    }
    __syncthreads();

    f32x4 acc1[4][4], accg[4][4];
#pragma unroll
    for (int i = 0; i < 4; ++i)
#pragma unroll
        for (int j = 0; j < 4; ++j) {
            acc1[i][j] = f32x4{0.f, 0.f, 0.f, 0.f};
            accg[i][j] = f32x4{0.f, 0.f, 0.f, 0.f};
        }

    const u16* w1e = w1h + (size_t)e * HDIM * CDIM;
    const u16* wge = wgh + (size_t)e * HDIM * CDIM;
    int wrow = wv >> 2, wcol = wv & 3;       // h-half, slot-quarter
    int lrow = lane & 15, lkg = lane >> 4;
    int sr = lane >> 2, sc = (lane & 3) * 8; // staging: 16 rows x 4x16B

    // hoisted per-lane global row pointers
    const u16* xrow[2] = {
        xh + (size_t)stok[wv * 32 + sr] * CDIM + sc,
        xh + (size_t)stok[wv * 32 + 16 + sr] * CDIM + sc };
    const u16* w1row = w1e + (size_t)(h0 + wv * 16 + sr) * CDIM + sc;
    const u16* wgrow = wge + (size_t)(h0 + wv * 16 + sr) * CDIM + sc;

    auto STAGE = [&](int b, int k0) {   // 4 loads per wave
#pragma unroll
        for (int h = 0; h < 2; ++h)
            gload16(&tX[b][(wv * 32 + h * 16) * BK], xrow[h] + k0);
        gload16(&tW1[b][(wv * 16) * BK], w1row + k0);
        gload16(&tWg[b][(wv * 16) * BK], wgrow + k0);
    };
    auto COMPUTE = [&](int b) {
        i32x4 xr[4], ar[4], gr[4];
#pragma unroll
        for (int j = 0; j < 4; ++j)
            xr[j] = *(const i32x4*)&tX[b][(wcol * 64 + j * 16 + lrow) * BK + lkg * 8];
#pragma unroll
        for (int i = 0; i < 4; ++i) {
            ar[i] = *(const i32x4*)&tW1[b][(wrow * 64 + i * 16 + lrow) * BK + lkg * 8];
            gr[i] = *(const i32x4*)&tWg[b][(wrow * 64 + i * 16 + lrow) * BK + lkg * 8];
        }
        __builtin_amdgcn_s_setprio(1);
#pragma unroll
        for (int i = 0; i < 4; ++i)
#pragma unroll
            for (int j = 0; j < 4; ++j) {
                acc1[i][j] = __builtin_amdgcn_mfma_f32_16x16x32_f16(
                    __builtin_bit_cast(f16x8, ar[i]), __builtin_bit_cast(f16x8, xr[j]),
                    acc1[i][j], 0, 0, 0);
                accg[i][j] = __builtin_amdgcn_mfma_f32_16x16x32_f16(
                    __builtin_bit_cast(f16x8, gr[i]), __builtin_bit_cast(f16x8, xr[j]),
                    accg[i][j], 0, 0, 0);
            }
        __builtin_amdgcn_s_setprio(0);
    };

    const int NT = CDIM / BK;   // 16
    STAGE(0, 0);
    STAGE(1, BK);
    int cur = 0;
#pragma unroll 1
    for (int t = 0; t < NT; ++t) {
        if (t + 1 < NT) { asm volatile("s_waitcnt vmcnt(4)" ::: "memory"); }
        else            { asm volatile("s_waitcnt vmcnt(0)" ::: "memory"); }
        __builtin_amdgcn_s_barrier();          // tile t landed for all waves
        __builtin_amdgcn_sched_barrier(0);
        COMPUTE(cur);
        __builtin_amdgcn_sched_barrier(0);
        __builtin_amdgcn_s_barrier();          // all waves done reading buf cur
        if (t + 2 < NT) STAGE(cur, (t + 2) * BK);
        cur ^= 1;
    }

    int vrows = cnt - r0;
    int hrow0 = (base - gbase) + r0;   // group-local slot row
#pragma unroll
    for (int j = 0; j < 4; ++j) {
        int tr = wcol * 64 + j * 16 + lrow;   // D col = slot row (0..255)
        if (tr < vrows) {
            size_t row = (size_t)(hrow0 + tr);
#pragma unroll
            for (int i = 0; i < 4; ++i) {
                int hc = h0 + wrow * 64 + i * 16 + lkg * 4;  // D row = h index
                u16x4 o;
#pragma unroll
                for (int r = 0; r < 4; ++r) {
                    float s = acc1[i][j][r];
                    float v = s * accg[i][j][r] / (1.f + __expf(-s));  // silu(s)*g
                    o[r] = f2h(v);
                }
                *(u16x4*)&hbuf[row * HDIM + hc] = o;
            }
        }
    }
}

// ---------------- FFN2: outPair[tok][k] = f16(gate * (h w2^T)) --------------
// 512-thread block, tile 256 slots x 256 cols, 8 waves; vmcnt(4) pipeline.
__global__ __launch_bounds__(512, 4) void k_ffn2(
    int e0, const u16* __restrict__ hbuf, const u16* __restrict__ w2h,
    const int* __restrict__ perm, const float* __restrict__ pgate,
    const int* __restrict__ offs, u16* __restrict__ outp) {
    int e  = e0 + (blockIdx.x >> 6);
    int rt = blockIdx.x & 63;
    int gbase = offs[e0];
    int base = offs[e];
    int cnt  = offs[e + 1] - base;
    if (cnt > SMAX) cnt = SMAX;
    int r0 = rt * 256;
    if (r0 >= cnt) return;
    int cb = blockIdx.y * 256;   // 256-col slab

    __shared__ u16 tH[2][256 * BK];   // 16 KB per buffer
    __shared__ u16 tW[2][256 * BK];   // 16 KB per buffer

    int tid = threadIdx.x, lane = tid & 63, wv = tid >> 6;
    int wrow = wv >> 2, wcol = wv & 3;   // col-64-base-half, slot-quarter
    int lrow = lane & 15, lkg = lane >> 4;
    int sr = lane >> 2, sc = (lane & 3) * 8;

    const u16* w2e = w2h + (size_t)e * CDIM * HDIM;
    const u16* hb  = hbuf + (size_t)((base - gbase) + r0) * HDIM;

    f32x4 acc[2][4][4];
#pragma unroll
    for (int ch = 0; ch < 2; ++ch)
#pragma unroll
        for (int i = 0; i < 4; ++i)
#pragma unroll
            for (int j = 0; j < 4; ++j) acc[ch][i][j] = f32x4{0.f, 0.f, 0.f, 0.f};

    auto STAGE = [&](int b, int k0) {   // 4 loads per wave
#pragma unroll
        for (int h = 0; h < 2; ++h) {
            int rb = wv * 32 + h * 16;
            gload16(&tH[b][rb * BK], hb  + (size_t)(rb + sr) * HDIM + k0 + sc);
            gload16(&tW[b][rb * BK], w2e + (size_t)(cb + rb + sr) * HDIM + k0 + sc);
        }
    };
    auto COMPUTE = [&](int b) {
        i32x4 hr[4];
#pragma unroll
        for (int j = 0; j < 4; ++j)
            hr[j] = *(const i32x4*)&tH[b][(wcol * 64 + j * 16 + lrow) * BK + lkg * 8];
#pragma unroll
        for (int ch = 0; ch < 2; ++ch) {
            i32x4 wr[4];
#pragma unroll
            for (int i = 0; i < 4; ++i)
                wr[i] = *(const i32x4*)&tW[b][(ch * 128 + wrow * 64 + i * 16 + lrow) * BK + lkg * 8];
            __builtin_amdgcn_s_setprio(1);
#pragma unroll
            for (int i = 0; i < 4; ++i)
#pragma unroll
                for (int j = 0; j < 4; ++j)
                    acc[ch][i][j] = __builtin_amdgcn_mfma_f32_16x16x32_f16(
                        __builtin_bit_cast(f16x8, wr[i]), __builtin_bit_cast(f16x8, hr[j]),
                        acc[ch][i][j], 0, 0, 0);
            __builtin_amdgcn_s_setprio(0);
        }
    };

    const int NT = HDIM / BK;   // 48
    STAGE(0, 0);
    STAGE(1, BK);
    int cur = 0;
#pragma unroll 1
    for (int t = 0; t < NT; ++t) {
        if (t + 1 < NT) { asm volatile("s_waitcnt vmcnt(4)" ::: "memory"); }
        else            { asm volatile("s_waitcnt vmcnt(0)" ::: "memory"); }
        __builtin_amdgcn_s_barrier();
        __builtin_amdgcn_sched_barrier(0);
        COMPUTE(cur);
        __builtin_amdgcn_sched_barrier(0);
        __builtin_amdgcn_s_barrier();
        if (t + 2 < NT) STAGE(cur, (t + 2) * BK);
        cur ^= 1;
    }

    int vrows = cnt - r0;
#pragma unroll
    for (int j = 0; j < 4; ++j) {
        int sr2 = wcol * 64 + j * 16 + lrow;   // slot (0..255)
        if (sr2 < vrows) {
            int slot = base + r0 + sr2;
            int pk = perm[slot];
            float g = pgate[slot];
            int tok = pk & 0x7fffffff;
            int kk = ((unsigned)pk) >> 31;
            u16* dstp = outp + ((size_t)tok * 2 + kk) * CDIM + cb;
#pragma unroll
            for (int ch = 0; ch < 2; ++ch) {
#pragma unroll
                for (int i = 0; i < 4; ++i) {
                    f32x4 v = acc[ch][i][j];
                    u16x4 o = { f2h(v[0] * g), f2h(v[1] * g),
                                f2h(v[2] * g), f2h(v[3] * g) };
                    *(u16x4*)(dstp + ch * 128 + wrow * 64 + i * 16 + lkg * 4) = o;
                }
            }
        }
    }
}

// ---------------- in-place combine: u16 pairs -> fp32 ----------------------
__global__ __launch_bounds__(256) void k_combine(float* __restrict__ out) {
    int gid = blockIdx.x * 256 + threadIdx.x;
    int tok = gid >> 6, lane = gid & 63;
    const u16* p = (const u16*)out + (size_t)tok * 2 * CDIM + lane * 8;
    u16x4 a0 = *(const u16x4*)p;
    u16x4 a1 = *(const u16x4*)(p + 4);
    u16x4 b0 = *(const u16x4*)(p + CDIM);
    u16x4 b1 = *(const u16x4*)(p + CDIM + 4);
    asm volatile("s_waitcnt vmcnt(0)" ::: "memory");
    f32x4 r0, r1;
#pragma unroll
    for (int r = 0; r < 4; ++r) {
        r0[r] = h2f(a0[r]) + h2f(b0[r]);
        r1[r] = h2f(a1[r]) + h2f(b1[r]);
    }
    float* d = out + (size_t)tok * CDIM + lane * 8;
    *(f32x4*)d = r0;
    *(f32x4*)(d + 4) = r1;
}

extern "C" void kernel_launch(void* const* d_in, const int* in_sizes, int n_in,
                              void* d_out, int out_size, void* d_ws, size_t ws_size,
                              hipStream_t stream) {
    const float* x  = (const float*)d_in[0];
    const float* rw = (const float*)d_in[1];
    const float* w1 = (const float*)d_in[2];
    const float* wg = (const float*)d_in[3];
    const float* w2 = (const float*)d_in[4];
    float* out = (float*)d_out;

    char* ws = (char*)d_ws;
    size_t o = 0;
    auto alloc = [&](size_t b) { size_t r = o; o += (b + 255) & ~(size_t)255; return r; };

    int* meta    = (int*)(ws + alloc(2048));
    int* counts  = meta;           // stride 16 per expert
    int* cursor  = meta + 128;     // stride 16 per expert
    int* offs    = meta + 256;     // contiguous [ENUM+1]
    int*   sel   = (int*)(ws + alloc((size_t)NTOK * 2 * 4));
    float* gate  = (float*)(ws + alloc((size_t)NTOK * 2 * 4));
    int*   perm  = (int*)(ws + alloc((size_t)NTOK * 2 * 4));
    float* pgate = (float*)(ws + alloc((size_t)NTOK * 2 * 4));
    u16* xh      = (u16*)(ws + alloc((size_t)NTOK * CDIM * 2));
    u16* w1h     = (u16*)(ws + alloc((size_t)ENUM * HDIM * CDIM * 2));
    u16* wgh     = (u16*)(ws + alloc((size_t)ENUM * HDIM * CDIM * 2));
    u16* w2h     = (u16*)(ws + alloc((size_t)ENUM * HDIM * CDIM * 2));
    size_t o_h   = o;   // hbuf (group-sequential reuse)
    u16* hbuf    = (u16*)(ws + o_h);

    const size_t h1 = (size_t)(2 * NTOK) * HDIM * 2;   // 201 MB
    const size_t h2 = (size_t)36864 * HDIM * 2;        // 113 MB
    const size_t h8 = (size_t)SMAX * HDIM * 2;         //  50 MB
    int ngroups;
    if      (o_h + h1 <= ws_size) ngroups = 1;
    else if (o_h + h2 <= ws_size) ngroups = 2;
    else if (o_h + h8 <= ws_size) ngroups = 8;
    else {
        k_diag<<<(out_size + 255) / 256, 256, 0, stream>>>(out, out_size);
        return;
    }
    int epg = ENUM / ngroups;

    k_zero<<<1, 256, 0, stream>>>(meta);
    k_router<<<NTOK / 4, 256, 0, stream>>>(x, rw, xh, sel, gate);
    k_convw<<<2048, 256, 0, stream>>>(w1, wg, w2, w1h, wgh, w2h);
    k_hist<<<NTOK * 2 / 1024, 256, 0, stream>>>(sel, counts);
    k_offsets<<<1, 64, 0, stream>>>(counts, offs);
    k_perm<<<NTOK * 2 / 512, 256, 0, stream>>>(sel, gate, offs, cursor, perm, pgate);

    for (int gi = 0; gi < ngroups; ++gi) {
        int e0 = gi * epg;
        k_ffn1<<<dim3(epg * (SMAX / 256), HDIM / 128), 512, 0, stream>>>(
            e0, xh, w1h, wgh, perm, offs, hbuf);
        k_ffn2<<<dim3(epg * (SMAX / 256), CDIM / 256), 512, 0, stream>>>(
            e0, hbuf, w2h, perm, pgate, offs, (u16*)out);
    }
    k_combine<<<NTOK / 4, 256, 0, stream>>>(out);
}

// Round 10
// 594.077 us; speedup vs baseline: 7.0552x; 7.0552x over previous
//
#include <hip/hip_runtime.h>
#include <hip/hip_bf16.h>
#include <math.h>

#define NTOK 32768
#define CDIM 512
#define HDIM 1536
#define ENUM 8
#define SMAX 16384   // per-expert row-tile span (actual counts ~8192)
#define BK 32        // K-step; 64B LDS rows -> conflict-free b128 banking

typedef unsigned short u16;
typedef _Float16 f16x8 __attribute__((ext_vector_type(8)));
typedef float    f32x4 __attribute__((ext_vector_type(4)));
typedef int      i32x4 __attribute__((ext_vector_type(4)));
typedef u16      u16x4 __attribute__((ext_vector_type(4)));

__device__ __forceinline__ void gload16(void* lds, const void* g) {
    __builtin_amdgcn_global_load_lds(
        (const __attribute__((address_space(1))) void*)g,
        (__attribute__((address_space(3))) void*)lds, 16, 0, 0);
}

__device__ __forceinline__ u16 f2h(float f) {
    _Float16 h = (_Float16)f;
    return __builtin_bit_cast(u16, h);
}
__device__ __forceinline__ float h2f(u16 u) {
    return (float)__builtin_bit_cast(_Float16, u);
}

// ---------------- meta ----------------
__global__ void k_zero(int* __restrict__ meta) {
    if (threadIdx.x < 256) meta[threadIdx.x] = 0;
}

__global__ void k_offsets(const int* __restrict__ counts, int* __restrict__ offs) {
    if (threadIdx.x == 0) {
        int o = 0;
        for (int e = 0; e < ENUM; ++e) { offs[e] = o; o += counts[e * 16]; }
        offs[ENUM] = o;
    }
}

__global__ void k_diag(float* __restrict__ out, int n) {
    int i = blockIdx.x * 256 + threadIdx.x;
    if (i < n) out[i] = 12345.0f;
}

// ---------------- router: logits, top-2, gates, x->f16 (no atomics) --------
__global__ __launch_bounds__(256) void k_router(
    const float* __restrict__ x, const float* __restrict__ rw,
    u16* __restrict__ xh, int* __restrict__ sel, float* __restrict__ gate) {
    __shared__ float srw[ENUM * CDIM];
    int tid = threadIdx.x;
    for (int i = tid * 4; i < ENUM * CDIM; i += 256 * 4)
        *(float4*)&srw[i] = *(const float4*)&rw[i];
    __syncthreads();

    int wave = tid >> 6, lane = tid & 63;
    int n = blockIdx.x * 4 + wave;

    const float* xr = x + (size_t)n * CDIM + lane * 8;
    float4 a = *(const float4*)xr;
    float4 b = *(const float4*)(xr + 4);

    u16x4 p0 = { f2h(a.x), f2h(a.y), f2h(a.z), f2h(a.w) };
    u16x4 p1 = { f2h(b.x), f2h(b.y), f2h(b.z), f2h(b.w) };
    u16* xd = xh + (size_t)n * CDIM + lane * 8;
    *(u16x4*)xd = p0;
    *(u16x4*)(xd + 4) = p1;

    float part[ENUM];
#pragma unroll
    for (int e = 0; e < ENUM; ++e) {
        const float4* rp = (const float4*)&srw[e * CDIM + lane * 8];
        float4 r0 = rp[0], r1 = rp[1];
        part[e] = a.x * r0.x + a.y * r0.y + a.z * r0.z + a.w * r0.w
                + b.x * r1.x + b.y * r1.y + b.z * r1.z + b.w * r1.w;
    }
#pragma unroll
    for (int m = 32; m >= 1; m >>= 1) {
#pragma unroll
        for (int e = 0; e < ENUM; ++e) part[e] += __shfl_xor(part[e], m, 64);
    }

    if (lane == 0) {
        int e0 = 0; float m0 = part[0];
#pragma unroll
        for (int e = 1; e < ENUM; ++e) { if (part[e] > m0) { m0 = part[e]; e0 = e; } }
        int e1 = -1; float m1 = -1e30f;
#pragma unroll
        for (int e = 0; e < ENUM; ++e) { if (e != e0 && part[e] > m1) { m1 = part[e]; e1 = e; } }
        float g0 = 1.f / (1.f + __expf(m1 - m0));
        sel[2 * n] = e0;  sel[2 * n + 1] = e1;
        gate[2 * n] = g0; gate[2 * n + 1] = 1.f - g0;
    }
}

// ---------------- histogram of sel -> padded counts ----------------
__global__ __launch_bounds__(256) void k_hist(const int* __restrict__ sel,
                                              int* __restrict__ counts) {
    __shared__ int lc[ENUM];
    int tid = threadIdx.x;
    if (tid < ENUM) lc[tid] = 0;
    __syncthreads();
    int i = blockIdx.x * 1024 + tid;
#pragma unroll
    for (int k = 0; k < 4; ++k) atomicAdd(&lc[sel[i + k * 256]], 1);
    __syncthreads();
    if (tid < ENUM) atomicAdd(&counts[tid * 16], lc[tid]);
}

// ---------------- weights fp32 -> f16 ----------------
__global__ void k_convw(const float* __restrict__ w1, const float* __restrict__ wg,
                        const float* __restrict__ w2, u16* __restrict__ w1h,
                        u16* __restrict__ wgh, u16* __restrict__ w2h) {
    const int total = ENUM * HDIM * CDIM / 4;
    for (int i = blockIdx.x * blockDim.x + threadIdx.x; i < total;
         i += gridDim.x * blockDim.x) {
        float4 a = ((const float4*)w1)[i];
        u16x4 o1 = { f2h(a.x), f2h(a.y), f2h(a.z), f2h(a.w) };
        ((u16x4*)w1h)[i] = o1;
        float4 c = ((const float4*)wg)[i];
        u16x4 o2 = { f2h(c.x), f2h(c.y), f2h(c.z), f2h(c.w) };
        ((u16x4*)wgh)[i] = o2;
        float4 d = ((const float4*)w2)[i];
        u16x4 o3 = { f2h(d.x), f2h(d.y), f2h(d.z), f2h(d.w) };
        ((u16x4*)w2h)[i] = o3;
    }
}

// ---------------- build per-expert gather lists (block-local ranking) -------
__global__ __launch_bounds__(256) void k_perm(
    const int* __restrict__ sel, const float* __restrict__ gate,
    const int* __restrict__ offs, int* __restrict__ cursor,
    int* __restrict__ perm, float* __restrict__ pgate) {
    __shared__ int lc[ENUM];
    __shared__ int lbase[ENUM];
    int tid = threadIdx.x;
    if (tid < ENUM) lc[tid] = 0;
    __syncthreads();
    int i0 = blockIdx.x * 512;
    int p0 = i0 + tid, p1 = i0 + 256 + tid;
    int e0 = sel[p0], e1 = sel[p1];
    int r0 = atomicAdd(&lc[e0], 1);
    int r1 = atomicAdd(&lc[e1], 1);
    __syncthreads();
    if (tid < ENUM) lbase[tid] = atomicAdd(&cursor[tid * 16], lc[tid]);
    __syncthreads();
    int s0 = offs[e0] + lbase[e0] + r0;
    int s1 = offs[e1] + lbase[e1] + r1;
    perm[s0] = (p0 >> 1) | ((p0 & 1) << 31);
    pgate[s0] = gate[p0];
    perm[s1] = (p1 >> 1) | ((p1 & 1) << 31);
    pgate[s1] = gate[p1];
}

// ---------------- FFN1: h = silu(x w1^T) * (x wg^T) ------------------------
// Round-8 core (256 thr, 2-deep vmcnt(6) pipeline). Grid: x = slot-tile,
// y = (expert-in-group)*12 + h-tile  -> co-resident blocks share one
// (e, h0) weight panel (L2-resident).
__global__ __launch_bounds__(256, 2) void k_ffn1(
    int e0, const u16* __restrict__ xh, const u16* __restrict__ w1h,
    const u16* __restrict__ wgh, const int* __restrict__ perm,
    const int* __restrict__ offs, u16* __restrict__ hbuf) {
    int e  = e0 + blockIdx.y / (HDIM / 128);
    int h0 = (blockIdx.y % (HDIM / 128)) * 128;
    int rt = blockIdx.x;
    int gbase = offs[e0];
    int base = offs[e];
    int cnt  = offs[e + 1] - base;
    if (cnt > SMAX) cnt = SMAX;
    int r0 = rt * 128;
    if (r0 >= cnt) return;

    __shared__ u16 tX[2][128 * BK];   // 8 KB per buffer
    __shared__ u16 tW1[2][128 * BK];
    __shared__ u16 tWg[2][128 * BK];
    __shared__ int stok[128];

    int tid = threadIdx.x, lane = tid & 63, wv = tid >> 6;
    if (tid < 128) {
        int r = r0 + tid;
        stok[tid] = (r < cnt) ? (perm[base + r] & 0x7fffffff) : 0;
    }
    __syncthreads();

    f32x4 acc1[4][4], accg[4][4];
#pragma unroll
    for (int i = 0; i < 4; ++i)
#pragma unroll
        for (int j = 0; j < 4; ++j) {
            acc1[i][j] = f32x4{0.f, 0.f, 0.f, 0.f};
            accg[i][j] = f32x4{0.f, 0.f, 0.f, 0.f};
        }

    const u16* w1e = w1h + (size_t)e * HDIM * CDIM;
    const u16* wge = wgh + (size_t)e * HDIM * CDIM;
    int wrow = wv >> 1, wcol = wv & 1;
    int lrow = lane & 15, lkg = lane >> 4;
    int sr = lane >> 2, sc = (lane & 3) * 8;   // staging: 16 rows x 4x16B

    const u16* xrow[2] = {
        xh + (size_t)stok[wv * 32 + sr] * CDIM + sc,
        xh + (size_t)stok[wv * 32 + 16 + sr] * CDIM + sc };
    const u16* w1row[2] = {
        w1e + (size_t)(h0 + wv * 32 + sr) * CDIM + sc,
        w1e + (size_t)(h0 + wv * 32 + 16 + sr) * CDIM + sc };
    const u16* wgrow[2] = {
        wge + (size_t)(h0 + wv * 32 + sr) * CDIM + sc,
        wge + (size_t)(h0 + wv * 32 + 16 + sr) * CDIM + sc };

    auto STAGE = [&](int b, int k0) {   // 6 loads per wave
#pragma unroll
        for (int h = 0; h < 2; ++h) {
            int rb = wv * 32 + h * 16;
            gload16(&tX[b][rb * BK],  xrow[h]  + k0);
            gload16(&tW1[b][rb * BK], w1row[h] + k0);
            gload16(&tWg[b][rb * BK], wgrow[h] + k0);
        }
    };
    auto COMPUTE = [&](int b) {
        i32x4 xr[4], ar[4], gr[4];
#pragma unroll
        for (int j = 0; j < 4; ++j)
            xr[j] = *(const i32x4*)&tX[b][(wcol * 64 + j * 16 + lrow) * BK + lkg * 8];
#pragma unroll
        for (int i = 0; i < 4; ++i) {
            ar[i] = *(const i32x4*)&tW1[b][(wrow * 64 + i * 16 + lrow) * BK + lkg * 8];
            gr[i] = *(const i32x4*)&tWg[b][(wrow * 64 + i * 16 + lrow) * BK + lkg * 8];
        }
#pragma unroll
        for (int i = 0; i < 4; ++i)
#pragma unroll
            for (int j = 0; j < 4; ++j) {
                acc1[i][j] = __builtin_amdgcn_mfma_f32_16x16x32_f16(
                    __builtin_bit_cast(f16x8, ar[i]), __builtin_bit_cast(f16x8, xr[j]),
                    acc1[i][j], 0, 0, 0);
                accg[i][j] = __builtin_amdgcn_mfma_f32_16x16x32_f16(
                    __builtin_bit_cast(f16x8, gr[i]), __builtin_bit_cast(f16x8, xr[j]),
                    accg[i][j], 0, 0, 0);
            }
    };

    const int NT = CDIM / BK;   // 16
    STAGE(0, 0);
    STAGE(1, BK);
    int cur = 0;
#pragma unroll 1
    for (int t = 0; t < NT; ++t) {
        if (t + 1 < NT) { asm volatile("s_waitcnt vmcnt(6)" ::: "memory"); }
        else            { asm volatile("s_waitcnt vmcnt(0)" ::: "memory"); }
        __builtin_amdgcn_s_barrier();          // tile t landed for all waves
        __builtin_amdgcn_sched_barrier(0);
        COMPUTE(cur);
        __builtin_amdgcn_sched_barrier(0);
        __builtin_amdgcn_s_barrier();          // all waves done reading buf cur
        if (t + 2 < NT) STAGE(cur, (t + 2) * BK);
        cur ^= 1;
    }

    int vrows = cnt - r0;
    int hrow0 = (base - gbase) + r0;   // group-local slot row
#pragma unroll
    for (int j = 0; j < 4; ++j) {
        int tr = wcol * 64 + j * 16 + lrow;   // D col = slot row
        if (tr < vrows) {
            size_t row = (size_t)(hrow0 + tr);
#pragma unroll
            for (int i = 0; i < 4; ++i) {
                int hc = h0 + wrow * 64 + i * 16 + lkg * 4;  // D row = h index
                u16x4 o;
#pragma unroll
                for (int r = 0; r < 4; ++r) {
                    float s = acc1[i][j][r];
                    float v = s * accg[i][j][r] / (1.f + __expf(-s));  // silu(s)*g
                    o[r] = f2h(v);
                }
                *(u16x4*)&hbuf[row * HDIM + hc] = o;
            }
        }
    }
}

// ---------------- FFN2: outPair[tok][k] = f16(gate * (h w2^T)) --------------
// Proven 128-col core + 2-deep vmcnt(4) pipeline. Grid: x = slot-tile,
// y = (expert-in-group)*4 + c-slab -> co-resident blocks share one 393 KB
// w2 slab (L2-resident).
__global__ __launch_bounds__(256, 2) void k_ffn2(
    int e0, const u16* __restrict__ hbuf, const u16* __restrict__ w2h,
    const int* __restrict__ perm, const float* __restrict__ pgate,
    const int* __restrict__ offs, u16* __restrict__ outp) {
    int e  = e0 + blockIdx.y / (CDIM / 128);
    int c0 = (blockIdx.y % (CDIM / 128)) * 128;
    int rt = blockIdx.x;
    int gbase = offs[e0];
    int base = offs[e];
    int cnt  = offs[e + 1] - base;
    if (cnt > SMAX) cnt = SMAX;
    int r0 = rt * 128;
    if (r0 >= cnt) return;

    __shared__ u16 tH[2][128 * BK];   // 8 KB per buffer
    __shared__ u16 tW[2][128 * BK];   // 8 KB per buffer

    int tid = threadIdx.x, lane = tid & 63, wv = tid >> 6;
    int wrow = wv >> 1, wcol = wv & 1;
    int lrow = lane & 15, lkg = lane >> 4;
    int sr = lane >> 2, sc = (lane & 3) * 8;

    const u16* w2e = w2h + (size_t)e * CDIM * HDIM;
    const u16* hb  = hbuf + (size_t)((base - gbase) + r0) * HDIM;

    f32x4 acc[4][4];
#pragma unroll
    for (int i = 0; i < 4; ++i)
#pragma unroll
        for (int j = 0; j < 4; ++j) acc[i][j] = f32x4{0.f, 0.f, 0.f, 0.f};

    auto STAGE = [&](int b, int k0) {   // 4 loads per wave
#pragma unroll
        for (int h = 0; h < 2; ++h) {
            int rb = wv * 32 + h * 16;
            gload16(&tH[b][rb * BK], hb  + (size_t)(rb + sr) * HDIM + k0 + sc);
            gload16(&tW[b][rb * BK], w2e + (size_t)(c0 + rb + sr) * HDIM + k0 + sc);
        }
    };
    auto COMPUTE = [&](int b) {
        i32x4 hr[4], wr[4];
#pragma unroll
        for (int j = 0; j < 4; ++j)
            hr[j] = *(const i32x4*)&tH[b][(wcol * 64 + j * 16 + lrow) * BK + lkg * 8];
#pragma unroll
        for (int i = 0; i < 4; ++i)
            wr[i] = *(const i32x4*)&tW[b][(wrow * 64 + i * 16 + lrow) * BK + lkg * 8];
#pragma unroll
        for (int i = 0; i < 4; ++i)
#pragma unroll
            for (int j = 0; j < 4; ++j)
                acc[i][j] = __builtin_amdgcn_mfma_f32_16x16x32_f16(
                    __builtin_bit_cast(f16x8, wr[i]), __builtin_bit_cast(f16x8, hr[j]),
                    acc[i][j], 0, 0, 0);
    };

    const int NT = HDIM / BK;   // 48
    STAGE(0, 0);
    STAGE(1, BK);
    int cur = 0;
#pragma unroll 1
    for (int t = 0; t < NT; ++t) {
        if (t + 1 < NT) { asm volatile("s_waitcnt vmcnt(4)" ::: "memory"); }
        else            { asm volatile("s_waitcnt vmcnt(0)" ::: "memory"); }
        __builtin_amdgcn_s_barrier();
        __builtin_amdgcn_sched_barrier(0);
        COMPUTE(cur);
        __builtin_amdgcn_sched_barrier(0);
        __builtin_amdgcn_s_barrier();
        if (t + 2 < NT) STAGE(cur, (t + 2) * BK);
        cur ^= 1;
    }

    int vrows = cnt - r0;
#pragma unroll
    for (int j = 0; j < 4; ++j) {
        int sr2 = wcol * 64 + j * 16 + lrow;
        if (sr2 < vrows) {
            int slot = base + r0 + sr2;
            int pk = perm[slot];
            float g = pgate[slot];
            int tok = pk & 0x7fffffff;
            int kk = ((unsigned)pk) >> 31;
            u16* dstp = outp + ((size_t)tok * 2 + kk) * CDIM
                      + c0 + wrow * 64 + lkg * 4;
#pragma unroll
            for (int i = 0; i < 4; ++i) {
                f32x4 v = acc[i][j];
                u16x4 o = { f2h(v[0] * g), f2h(v[1] * g),
                            f2h(v[2] * g), f2h(v[3] * g) };
                *(u16x4*)(dstp + i * 16) = o;
            }
        }
    }
}

// ---------------- in-place combine: u16 pairs -> fp32 ----------------------
__global__ __launch_bounds__(256) void k_combine(float* __restrict__ out) {
    int gid = blockIdx.x * 256 + threadIdx.x;
    int tok = gid >> 6, lane = gid & 63;
    const u16* p = (const u16*)out + (size_t)tok * 2 * CDIM + lane * 8;
    u16x4 a0 = *(const u16x4*)p;
    u16x4 a1 = *(const u16x4*)(p + 4);
    u16x4 b0 = *(const u16x4*)(p + CDIM);
    u16x4 b1 = *(const u16x4*)(p + CDIM + 4);
    asm volatile("s_waitcnt vmcnt(0)" ::: "memory");
    f32x4 r0, r1;
#pragma unroll
    for (int r = 0; r < 4; ++r) {
        r0[r] = h2f(a0[r]) + h2f(b0[r]);
        r1[r] = h2f(a1[r]) + h2f(b1[r]);
    }
    float* d = out + (size_t)tok * CDIM + lane * 8;
    *(f32x4*)d = r0;
    *(f32x4*)(d + 4) = r1;
}

extern "C" void kernel_launch(void* const* d_in, const int* in_sizes, int n_in,
                              void* d_out, int out_size, void* d_ws, size_t ws_size,
                              hipStream_t stream) {
    const float* x  = (const float*)d_in[0];
    const float* rw = (const float*)d_in[1];
    const float* w1 = (const float*)d_in[2];
    const float* wg = (const float*)d_in[3];
    const float* w2 = (const float*)d_in[4];
    float* out = (float*)d_out;

    char* ws = (char*)d_ws;
    size_t o = 0;
    auto alloc = [&](size_t b) { size_t r = o; o += (b + 255) & ~(size_t)255; return r; };

    int* meta    = (int*)(ws + alloc(2048));
    int* counts  = meta;           // stride 16 per expert
    int* cursor  = meta + 128;     // stride 16 per expert
    int* offs    = meta + 256;     // contiguous [ENUM+1]
    int*   sel   = (int*)(ws + alloc((size_t)NTOK * 2 * 4));
    float* gate  = (float*)(ws + alloc((size_t)NTOK * 2 * 4));
    int*   perm  = (int*)(ws + alloc((size_t)NTOK * 2 * 4));
    float* pgate = (float*)(ws + alloc((size_t)NTOK * 2 * 4));
    u16* xh      = (u16*)(ws + alloc((size_t)NTOK * CDIM * 2));
    u16* w1h     = (u16*)(ws + alloc((size_t)ENUM * HDIM * CDIM * 2));
    u16* wgh     = (u16*)(ws + alloc((size_t)ENUM * HDIM * CDIM * 2));
    u16* w2h     = (u16*)(ws + alloc((size_t)ENUM * HDIM * CDIM * 2));
    size_t o_h   = o;   // hbuf (group-sequential reuse)
    u16* hbuf    = (u16*)(ws + o_h);

    const size_t h1 = (size_t)(2 * NTOK) * HDIM * 2;   // 201 MB
    const size_t h2 = (size_t)36864 * HDIM * 2;        // 113 MB
    const size_t h8 = (size_t)SMAX * HDIM * 2;         //  50 MB
    int ngroups;
    if      (o_h + h1 <= ws_size) ngroups = 1;
    else if (o_h + h2 <= ws_size) ngroups = 2;
    else if (o_h + h8 <= ws_size) ngroups = 8;
    else {
        k_diag<<<(out_size + 255) / 256, 256, 0, stream>>>(out, out_size);
        return;
    }
    int epg = ENUM / ngroups;

    k_zero<<<1, 256, 0, stream>>>(meta);
    k_router<<<NTOK / 4, 256, 0, stream>>>(x, rw, xh, sel, gate);
    k_convw<<<2048, 256, 0, stream>>>(w1, wg, w2, w1h, wgh, w2h);
    k_hist<<<NTOK * 2 / 1024, 256, 0, stream>>>(sel, counts);
    k_offsets<<<1, 64, 0, stream>>>(counts, offs);
    k_perm<<<NTOK * 2 / 512, 256, 0, stream>>>(sel, gate, offs, cursor, perm, pgate);

    for (int gi = 0; gi < ngroups; ++gi) {
        int e0 = gi * epg;
        k_ffn1<<<dim3(SMAX / 128, epg * (HDIM / 128)), 256, 0, stream>>>(
            e0, xh, w1h, wgh, perm, offs, hbuf);
        k_ffn2<<<dim3(SMAX / 128, epg * (CDIM / 128)), 256, 0, stream>>>(
            e0, hbuf, w2h, perm, pgate, offs, (u16*)out);
    }
    k_combine<<<NTOK / 4, 256, 0, stream>>>(out);
}

// Round 11
// 583.683 us; speedup vs baseline: 7.1808x; 1.0178x over previous
//
#include <hip/hip_runtime.h>
#include <hip/hip_bf16.h>
#include <math.h>

#define NTOK 32768
#define CDIM 512
#define HDIM 1536
#define ENUM 8
#define SMAX 16384   // per-expert row-tile span (actual counts ~8192)
#define BK 32        // K-step; 64B LDS rows

typedef unsigned short u16;
typedef _Float16 f16x8 __attribute__((ext_vector_type(8)));
typedef float    f32x4 __attribute__((ext_vector_type(4)));
typedef int      i32x4 __attribute__((ext_vector_type(4)));
typedef u16      u16x4 __attribute__((ext_vector_type(4)));

__device__ __forceinline__ void gload16(void* lds, const void* g) {
    __builtin_amdgcn_global_load_lds(
        (const __attribute__((address_space(1))) void*)g,
        (__attribute__((address_space(3))) void*)lds, 16, 0, 0);
}

__device__ __forceinline__ u16 f2h(float f) {
    _Float16 h = (_Float16)f;
    return __builtin_bit_cast(u16, h);
}
__device__ __forceinline__ float h2f(u16 u) {
    return (float)__builtin_bit_cast(_Float16, u);
}

// ---------------- meta ----------------
__global__ void k_zero(int* __restrict__ meta) {
    if (threadIdx.x < 256) meta[threadIdx.x] = 0;
}

__global__ void k_offsets(const int* __restrict__ counts, int* __restrict__ offs) {
    if (threadIdx.x == 0) {
        int o = 0;
        for (int e = 0; e < ENUM; ++e) { offs[e] = o; o += counts[e * 16]; }
        offs[ENUM] = o;
    }
}

__global__ void k_diag(float* __restrict__ out, int n) {
    int i = blockIdx.x * 256 + threadIdx.x;
    if (i < n) out[i] = 12345.0f;
}

// ---------------- router: logits, top-2, gates, x->f16 (no atomics) --------
__global__ __launch_bounds__(256) void k_router(
    const float* __restrict__ x, const float* __restrict__ rw,
    u16* __restrict__ xh, int* __restrict__ sel, float* __restrict__ gate) {
    __shared__ float srw[ENUM * CDIM];
    int tid = threadIdx.x;
    for (int i = tid * 4; i < ENUM * CDIM; i += 256 * 4)
        *(float4*)&srw[i] = *(const float4*)&rw[i];
    __syncthreads();

    int wave = tid >> 6, lane = tid & 63;
    int n = blockIdx.x * 4 + wave;

    const float* xr = x + (size_t)n * CDIM + lane * 8;
    float4 a = *(const float4*)xr;
    float4 b = *(const float4*)(xr + 4);

    u16x4 p0 = { f2h(a.x), f2h(a.y), f2h(a.z), f2h(a.w) };
    u16x4 p1 = { f2h(b.x), f2h(b.y), f2h(b.z), f2h(b.w) };
    u16* xd = xh + (size_t)n * CDIM + lane * 8;
    *(u16x4*)xd = p0;
    *(u16x4*)(xd + 4) = p1;

    float part[ENUM];
#pragma unroll
    for (int e = 0; e < ENUM; ++e) {
        const float4* rp = (const float4*)&srw[e * CDIM + lane * 8];
        float4 r0 = rp[0], r1 = rp[1];
        part[e] = a.x * r0.x + a.y * r0.y + a.z * r0.z + a.w * r0.w
                + b.x * r1.x + b.y * r1.y + b.z * r1.z + b.w * r1.w;
    }
#pragma unroll
    for (int m = 32; m >= 1; m >>= 1) {
#pragma unroll
        for (int e = 0; e < ENUM; ++e) part[e] += __shfl_xor(part[e], m, 64);
    }

    if (lane == 0) {
        int e0 = 0; float m0 = part[0];
#pragma unroll
        for (int e = 1; e < ENUM; ++e) { if (part[e] > m0) { m0 = part[e]; e0 = e; } }
        int e1 = -1; float m1 = -1e30f;
#pragma unroll
        for (int e = 0; e < ENUM; ++e) { if (e != e0 && part[e] > m1) { m1 = part[e]; e1 = e; } }
        float g0 = 1.f / (1.f + __expf(m1 - m0));
        sel[2 * n] = e0;  sel[2 * n + 1] = e1;
        gate[2 * n] = g0; gate[2 * n + 1] = 1.f - g0;
    }
}

// ---------------- histogram of sel -> padded counts ----------------
__global__ __launch_bounds__(256) void k_hist(const int* __restrict__ sel,
                                              int* __restrict__ counts) {
    __shared__ int lc[ENUM];
    int tid = threadIdx.x;
    if (tid < ENUM) lc[tid] = 0;
    __syncthreads();
    int i = blockIdx.x * 1024 + tid;
#pragma unroll
    for (int k = 0; k < 4; ++k) atomicAdd(&lc[sel[i + k * 256]], 1);
    __syncthreads();
    if (tid < ENUM) atomicAdd(&counts[tid * 16], lc[tid]);
}

// ---------------- weights fp32 -> f16 ----------------
__global__ void k_convw(const float* __restrict__ w1, const float* __restrict__ wg,
                        const float* __restrict__ w2, u16* __restrict__ w1h,
                        u16* __restrict__ wgh, u16* __restrict__ w2h) {
    const int total = ENUM * HDIM * CDIM / 4;
    for (int i = blockIdx.x * blockDim.x + threadIdx.x; i < total;
         i += gridDim.x * blockDim.x) {
        float4 a = ((const float4*)w1)[i];
        u16x4 o1 = { f2h(a.x), f2h(a.y), f2h(a.z), f2h(a.w) };
        ((u16x4*)w1h)[i] = o1;
        float4 c = ((const float4*)wg)[i];
        u16x4 o2 = { f2h(c.x), f2h(c.y), f2h(c.z), f2h(c.w) };
        ((u16x4*)wgh)[i] = o2;
        float4 d = ((const float4*)w2)[i];
        u16x4 o3 = { f2h(d.x), f2h(d.y), f2h(d.z), f2h(d.w) };
        ((u16x4*)w2h)[i] = o3;
    }
}

// ---------------- build per-expert gather lists (block-local ranking) -------
__global__ __launch_bounds__(256) void k_perm(
    const int* __restrict__ sel, const float* __restrict__ gate,
    const int* __restrict__ offs, int* __restrict__ cursor,
    int* __restrict__ perm, float* __restrict__ pgate) {
    __shared__ int lc[ENUM];
    __shared__ int lbase[ENUM];
    int tid = threadIdx.x;
    if (tid < ENUM) lc[tid] = 0;
    __syncthreads();
    int i0 = blockIdx.x * 512;
    int p0 = i0 + tid, p1 = i0 + 256 + tid;
    int e0 = sel[p0], e1 = sel[p1];
    int r0 = atomicAdd(&lc[e0], 1);
    int r1 = atomicAdd(&lc[e1], 1);
    __syncthreads();
    if (tid < ENUM) lbase[tid] = atomicAdd(&cursor[tid * 16], lc[tid]);
    __syncthreads();
    int s0 = offs[e0] + lbase[e0] + r0;
    int s1 = offs[e1] + lbase[e1] + r1;
    perm[s0] = (p0 >> 1) | ((p0 & 1) << 31);
    pgate[s0] = gate[p0];
    perm[s1] = (p1 >> 1) | ((p1 & 1) << 31);
    pgate[s1] = gate[p1];
}

// ---------------- FFN1: h = silu(x w1^T) * (x wg^T) ------------------------
// 2-deep vmcnt(6) pipeline + T2 chunk-swizzle: LDS row r's four 16B chunks
// are permuted by chunk ^= (r>>1)&3 via pre-swizzled global source (linear
// LDS dest, rule #21); reads XOR the same term -> 2-way banks (free).
__global__ __launch_bounds__(256, 2) void k_ffn1(
    int e0, const u16* __restrict__ xh, const u16* __restrict__ w1h,
    const u16* __restrict__ wgh, const int* __restrict__ perm,
    const int* __restrict__ offs, u16* __restrict__ hbuf) {
    int e  = e0 + blockIdx.y / (HDIM / 128);
    int h0 = (blockIdx.y % (HDIM / 128)) * 128;
    int rt = blockIdx.x;
    int gbase = offs[e0];
    int base = offs[e];
    int cnt  = offs[e + 1] - base;
    if (cnt > SMAX) cnt = SMAX;
    int r0 = rt * 128;
    if (r0 >= cnt) return;

    __shared__ u16 tX[2][128 * BK];   // 8 KB per buffer
    __shared__ u16 tW1[2][128 * BK];
    __shared__ u16 tWg[2][128 * BK];
    __shared__ int stok[128];

    int tid = threadIdx.x, lane = tid & 63, wv = tid >> 6;
    if (tid < 128) {
        int r = r0 + tid;
        stok[tid] = (r < cnt) ? (perm[base + r] & 0x7fffffff) : 0;
    }
    __syncthreads();

    f32x4 acc1[4][4], accg[4][4];
#pragma unroll
    for (int i = 0; i < 4; ++i)
#pragma unroll
        for (int j = 0; j < 4; ++j) {
            acc1[i][j] = f32x4{0.f, 0.f, 0.f, 0.f};
            accg[i][j] = f32x4{0.f, 0.f, 0.f, 0.f};
        }

    const u16* w1e = w1h + (size_t)e * HDIM * CDIM;
    const u16* wge = wgh + (size_t)e * HDIM * CDIM;
    int wrow = wv >> 1, wcol = wv & 1;
    int lrow = lane & 15, lkg = lane >> 4;
    int sr = lane >> 2;                                   // staging row 0..15
    int scs = (((lane & 3) ^ ((sr >> 1) & 3)) * 8);       // swizzled src chunk
    int lkgs = lkg ^ ((lrow >> 1) & 3);                   // swizzled read chunk

    const u16* xrow[2] = {
        xh + (size_t)stok[wv * 32 + sr] * CDIM + scs,
        xh + (size_t)stok[wv * 32 + 16 + sr] * CDIM + scs };
    const u16* w1row[2] = {
        w1e + (size_t)(h0 + wv * 32 + sr) * CDIM + scs,
        w1e + (size_t)(h0 + wv * 32 + 16 + sr) * CDIM + scs };
    const u16* wgrow[2] = {
        wge + (size_t)(h0 + wv * 32 + sr) * CDIM + scs,
        wge + (size_t)(h0 + wv * 32 + 16 + sr) * CDIM + scs };

    auto STAGE = [&](int b, int k0) {   // 6 loads per wave
#pragma unroll
        for (int h = 0; h < 2; ++h) {
            int rb = wv * 32 + h * 16;
            gload16(&tX[b][rb * BK],  xrow[h]  + k0);
            gload16(&tW1[b][rb * BK], w1row[h] + k0);
            gload16(&tWg[b][rb * BK], wgrow[h] + k0);
        }
    };
    auto COMPUTE = [&](int b) {
        i32x4 xr[4], ar[4], gr[4];
#pragma unroll
        for (int j = 0; j < 4; ++j)
            xr[j] = *(const i32x4*)&tX[b][(wcol * 64 + j * 16 + lrow) * BK + lkgs * 8];
#pragma unroll
        for (int i = 0; i < 4; ++i) {
            ar[i] = *(const i32x4*)&tW1[b][(wrow * 64 + i * 16 + lrow) * BK + lkgs * 8];
            gr[i] = *(const i32x4*)&tWg[b][(wrow * 64 + i * 16 + lrow) * BK + lkgs * 8];
        }
#pragma unroll
        for (int i = 0; i < 4; ++i)
#pragma unroll
            for (int j = 0; j < 4; ++j) {
                acc1[i][j] = __builtin_amdgcn_mfma_f32_16x16x32_f16(
                    __builtin_bit_cast(f16x8, ar[i]), __builtin_bit_cast(f16x8, xr[j]),
                    acc1[i][j], 0, 0, 0);
                accg[i][j] = __builtin_amdgcn_mfma_f32_16x16x32_f16(
                    __builtin_bit_cast(f16x8, gr[i]), __builtin_bit_cast(f16x8, xr[j]),
                    accg[i][j], 0, 0, 0);
            }
    };

    const int NT = CDIM / BK;   // 16
    STAGE(0, 0);
    STAGE(1, BK);
    int cur = 0;
#pragma unroll 1
    for (int t = 0; t < NT; ++t) {
        if (t + 1 < NT) { asm volatile("s_waitcnt vmcnt(6)" ::: "memory"); }
        else            { asm volatile("s_waitcnt vmcnt(0)" ::: "memory"); }
        __builtin_amdgcn_s_barrier();          // tile t landed for all waves
        __builtin_amdgcn_sched_barrier(0);
        COMPUTE(cur);
        __builtin_amdgcn_sched_barrier(0);
        __builtin_amdgcn_s_barrier();          // all waves done reading buf cur
        if (t + 2 < NT) STAGE(cur, (t + 2) * BK);
        cur ^= 1;
    }

    int vrows = cnt - r0;
    int hrow0 = (base - gbase) + r0;   // group-local slot row
#pragma unroll
    for (int j = 0; j < 4; ++j) {
        int tr = wcol * 64 + j * 16 + lrow;   // D col = slot row
        if (tr < vrows) {
            size_t row = (size_t)(hrow0 + tr);
#pragma unroll
            for (int i = 0; i < 4; ++i) {
                int hc = h0 + wrow * 64 + i * 16 + lkg * 4;  // D row = h index
                u16x4 o;
#pragma unroll
                for (int r = 0; r < 4; ++r) {
                    float s = acc1[i][j][r];
                    float v = s * accg[i][j][r] / (1.f + __expf(-s));  // silu(s)*g
                    o[r] = f2h(v);
                }
                *(u16x4*)&hbuf[row * HDIM + hc] = o;
            }
        }
    }
}

// ---------------- FFN2: outPair[tok][k] = f16(gate * (h w2^T)) --------------
// Same T2 chunk-swizzle; 2-deep vmcnt(4) pipeline; grid.y = (e, c-slab).
__global__ __launch_bounds__(256, 2) void k_ffn2(
    int e0, const u16* __restrict__ hbuf, const u16* __restrict__ w2h,
    const int* __restrict__ perm, const float* __restrict__ pgate,
    const int* __restrict__ offs, u16* __restrict__ outp) {
    int e  = e0 + blockIdx.y / (CDIM / 128);
    int c0 = (blockIdx.y % (CDIM / 128)) * 128;
    int rt = blockIdx.x;
    int gbase = offs[e0];
    int base = offs[e];
    int cnt  = offs[e + 1] - base;
    if (cnt > SMAX) cnt = SMAX;
    int r0 = rt * 128;
    if (r0 >= cnt) return;

    __shared__ u16 tH[2][128 * BK];   // 8 KB per buffer
    __shared__ u16 tW[2][128 * BK];   // 8 KB per buffer

    int tid = threadIdx.x, lane = tid & 63, wv = tid >> 6;
    int wrow = wv >> 1, wcol = wv & 1;
    int lrow = lane & 15, lkg = lane >> 4;
    int sr = lane >> 2;
    int scs = (((lane & 3) ^ ((sr >> 1) & 3)) * 8);
    int lkgs = lkg ^ ((lrow >> 1) & 3);

    const u16* w2e = w2h + (size_t)e * CDIM * HDIM;
    const u16* hb  = hbuf + (size_t)((base - gbase) + r0) * HDIM;

    f32x4 acc[4][4];
#pragma unroll
    for (int i = 0; i < 4; ++i)
#pragma unroll
        for (int j = 0; j < 4; ++j) acc[i][j] = f32x4{0.f, 0.f, 0.f, 0.f};

    auto STAGE = [&](int b, int k0) {   // 4 loads per wave
#pragma unroll
        for (int h = 0; h < 2; ++h) {
            int rb = wv * 32 + h * 16;
            gload16(&tH[b][rb * BK], hb  + (size_t)(rb + sr) * HDIM + k0 + scs);
            gload16(&tW[b][rb * BK], w2e + (size_t)(c0 + rb + sr) * HDIM + k0 + scs);
        }
    };
    auto COMPUTE = [&](int b) {
        i32x4 hr[4], wr[4];
#pragma unroll
        for (int j = 0; j < 4; ++j)
            hr[j] = *(const i32x4*)&tH[b][(wcol * 64 + j * 16 + lrow) * BK + lkgs * 8];
#pragma unroll
        for (int i = 0; i < 4; ++i)
            wr[i] = *(const i32x4*)&tW[b][(wrow * 64 + i * 16 + lrow) * BK + lkgs * 8];
#pragma unroll
        for (int i = 0; i < 4; ++i)
#pragma unroll
            for (int j = 0; j < 4; ++j)
                acc[i][j] = __builtin_amdgcn_mfma_f32_16x16x32_f16(
                    __builtin_bit_cast(f16x8, wr[i]), __builtin_bit_cast(f16x8, hr[j]),
                    acc[i][j], 0, 0, 0);
    };

    const int NT = HDIM / BK;   // 48
    STAGE(0, 0);
    STAGE(1, BK);
    int cur = 0;
#pragma unroll 1
    for (int t = 0; t < NT; ++t) {
        if (t + 1 < NT) { asm volatile("s_waitcnt vmcnt(4)" ::: "memory"); }
        else            { asm volatile("s_waitcnt vmcnt(0)" ::: "memory"); }
        __builtin_amdgcn_s_barrier();
        __builtin_amdgcn_sched_barrier(0);
        COMPUTE(cur);
        __builtin_amdgcn_sched_barrier(0);
        __builtin_amdgcn_s_barrier();
        if (t + 2 < NT) STAGE(cur, (t + 2) * BK);
        cur ^= 1;
    }

    int vrows = cnt - r0;
#pragma unroll
    for (int j = 0; j < 4; ++j) {
        int sr2 = wcol * 64 + j * 16 + lrow;
        if (sr2 < vrows) {
            int slot = base + r0 + sr2;
            int pk = perm[slot];
            float g = pgate[slot];
            int tok = pk & 0x7fffffff;
            int kk = ((unsigned)pk) >> 31;
            u16* dstp = outp + ((size_t)tok * 2 + kk) * CDIM
                      + c0 + wrow * 64 + lkg * 4;
#pragma unroll
            for (int i = 0; i < 4; ++i) {
                f32x4 v = acc[i][j];
                u16x4 o = { f2h(v[0] * g), f2h(v[1] * g),
                            f2h(v[2] * g), f2h(v[3] * g) };
                *(u16x4*)(dstp + i * 16) = o;
            }
        }
    }
}

// ---------------- in-place combine: u16 pairs -> fp32 ----------------------
__global__ __launch_bounds__(256) void k_combine(float* __restrict__ out) {
    int gid = blockIdx.x * 256 + threadIdx.x;
    int tok = gid >> 6, lane = gid & 63;
    const u16* p = (const u16*)out + (size_t)tok * 2 * CDIM + lane * 8;
    u16x4 a0 = *(const u16x4*)p;
    u16x4 a1 = *(const u16x4*)(p + 4);
    u16x4 b0 = *(const u16x4*)(p + CDIM);
    u16x4 b1 = *(const u16x4*)(p + CDIM + 4);
    asm volatile("s_waitcnt vmcnt(0)" ::: "memory");
    f32x4 r0, r1;
#pragma unroll
    for (int r = 0; r < 4; ++r) {
        r0[r] = h2f(a0[r]) + h2f(b0[r]);
        r1[r] = h2f(a1[r]) + h2f(b1[r]);
    }
    float* d = out + (size_t)tok * CDIM + lane * 8;
    *(f32x4*)d = r0;
    *(f32x4*)(d + 4) = r1;
}

extern "C" void kernel_launch(void* const* d_in, const int* in_sizes, int n_in,
                              void* d_out, int out_size, void* d_ws, size_t ws_size,
                              hipStream_t stream) {
    const float* x  = (const float*)d_in[0];
    const float* rw = (const float*)d_in[1];
    const float* w1 = (const float*)d_in[2];
    const float* wg = (const float*)d_in[3];
    const float* w2 = (const float*)d_in[4];
    float* out = (float*)d_out;

    char* ws = (char*)d_ws;
    size_t o = 0;
    auto alloc = [&](size_t b) { size_t r = o; o += (b + 255) & ~(size_t)255; return r; };

    int* meta    = (int*)(ws + alloc(2048));
    int* counts  = meta;           // stride 16 per expert
    int* cursor  = meta + 128;     // stride 16 per expert
    int* offs    = meta + 256;     // contiguous [ENUM+1]
    int*   sel   = (int*)(ws + alloc((size_t)NTOK * 2 * 4));
    float* gate  = (float*)(ws + alloc((size_t)NTOK * 2 * 4));
    int*   perm  = (int*)(ws + alloc((size_t)NTOK * 2 * 4));
    float* pgate = (float*)(ws + alloc((size_t)NTOK * 2 * 4));
    u16* xh      = (u16*)(ws + alloc((size_t)NTOK * CDIM * 2));
    u16* w1h     = (u16*)(ws + alloc((size_t)ENUM * HDIM * CDIM * 2));
    u16* wgh     = (u16*)(ws + alloc((size_t)ENUM * HDIM * CDIM * 2));
    u16* w2h     = (u16*)(ws + alloc((size_t)ENUM * HDIM * CDIM * 2));
    size_t o_h   = o;   // hbuf (group-sequential reuse)
    u16* hbuf    = (u16*)(ws + o_h);

    const size_t h1 = (size_t)(2 * NTOK) * HDIM * 2;   // 201 MB
    const size_t h2 = (size_t)36864 * HDIM * 2;        // 113 MB
    const size_t h8 = (size_t)SMAX * HDIM * 2;         //  50 MB
    int ngroups;
    if      (o_h + h1 <= ws_size) ngroups = 1;
    else if (o_h + h2 <= ws_size) ngroups = 2;
    else if (o_h + h8 <= ws_size) ngroups = 8;
    else {
        k_diag<<<(out_size + 255) / 256, 256, 0, stream>>>(out, out_size);
        return;
    }
    int epg = ENUM / ngroups;

    k_zero<<<1, 256, 0, stream>>>(meta);
    k_router<<<NTOK / 4, 256, 0, stream>>>(x, rw, xh, sel, gate);
    k_convw<<<2048, 256, 0, stream>>>(w1, wg, w2, w1h, wgh, w2h);
    k_hist<<<NTOK * 2 / 1024, 256, 0, stream>>>(sel, counts);
    k_offsets<<<1, 64, 0, stream>>>(counts, offs);
    k_perm<<<NTOK * 2 / 512, 256, 0, stream>>>(sel, gate, offs, cursor, perm, pgate);

    for (int gi = 0; gi < ngroups; ++gi) {
        int e0 = gi * epg;
        k_ffn1<<<dim3(SMAX / 128, epg * (HDIM / 128)), 256, 0, stream>>>(
            e0, xh, w1h, wgh, perm, offs, hbuf);
        k_ffn2<<<dim3(SMAX / 128, epg * (CDIM / 128)), 256, 0, stream>>>(
            e0, hbuf, w2h, perm, pgate, offs, (u16*)out);
    }
    k_combine<<<NTOK / 4, 256, 0, stream>>>(out);
}